// Round 2
// baseline (3443.421 us; speedup 1.0000x reference)
//
#include <hip/hip_runtime.h>
#include <math.h>

// Problem constants (fixed by the reference)
constexpr int NN  = 50000;   // nodes
constexpr int NE  = 600000;  // edges
constexpr int D   = 128;     // DIM == HID
constexpr int IND = 392;     // 3*DIM + TEMB

__device__ __forceinline__ float4 ld4(const float* p) { return *reinterpret_cast<const float4*>(p); }
__device__ __forceinline__ void   st4(float* p, float4 v) { *reinterpret_cast<float4*>(p) = v; }

// ---------------------------------------------------------------------------
// GEMM tile core: C[R rows][128 outs] += X[R][128k] * W[128 outs][128k]^T
// per-thread register tile: R rows x 8 outputs. X in LDS (rows padded to 132).
// ---------------------------------------------------------------------------
template <int R>
__device__ __forceinline__ void gemm_tile(const float (*X)[132],
                                          const float* __restrict__ W, int ldw,
                                          int r0, int o0, float acc[R][8])
{
#pragma unroll 2
  for (int k = 0; k < 128; k += 4) {
    float4 x[R];
#pragma unroll
    for (int i = 0; i < R; ++i) x[i] = ld4(&X[r0 + i][k]);
#pragma unroll
    for (int j = 0; j < 8; ++j) {
      float4 w = ld4(&W[(o0 + j) * ldw + k]);
#pragma unroll
      for (int i = 0; i < R; ++i) {
        acc[i][j] = fmaf(x[i].x, w.x, acc[i][j]);
        acc[i][j] = fmaf(x[i].y, w.y, acc[i][j]);
        acc[i][j] = fmaf(x[i].z, w.z, acc[i][j]);
        acc[i][j] = fmaf(x[i].w, w.w, acc[i][j]);
      }
    }
  }
}

template <int R>
__device__ __forceinline__ void zero_acc(float acc[R][8]) {
#pragma unroll
  for (int i = 0; i < R; ++i)
#pragma unroll
    for (int j = 0; j < 8; ++j) acc[i][j] = 0.0f;
}

// ---------------------------------------------------------------------------
// K1: per-node precompute. 32-node tiles (LDS 17KB -> 8 blocks/CU).
//   A[n]  = ew1[:,   0:128] . z[n]
//   B[n]  = ew1[:, 128:256] . z[n]
//   M[n]  = mw2 . relu(mw1 . z[n] + mb1) + mb2
// ---------------------------------------------------------------------------
__global__ __launch_bounds__(256, 8) void k_node(
    const float* __restrict__ z, const float* __restrict__ ew1,
    const float* __restrict__ mw1, const float* __restrict__ mb1,
    const float* __restrict__ mw2, const float* __restrict__ mb2,
    float* __restrict__ A, float* __restrict__ B, float* __restrict__ M)
{
  __shared__ float X[32][132];
  const int t  = threadIdx.x;
  const int n0 = blockIdx.x * 32;

  // stage z tile (32 consecutive lanes cover one 512B row -> coalesced)
#pragma unroll
  for (int c = 0; c < 4; ++c) {
    int f = c * 256 + t, r = f >> 5, c4 = f & 31;
    float4 v = make_float4(0.f, 0.f, 0.f, 0.f);
    if (n0 + r < NN) v = ld4(&z[(size_t)(n0 + r) * D + c4 * 4]);
    st4(&X[r][c4 * 4], v);
  }
  __syncthreads();

  const int r0 = (t >> 4) * 2;  // row-group base (0..30)
  const int o0 = (t & 15) * 8;  // out-group base
  float acc[2][8];

  // ---- A ----
  zero_acc<2>(acc);
  gemm_tile<2>(X, ew1, IND, r0, o0, acc);
#pragma unroll
  for (int i = 0; i < 2; ++i) {
    int n = n0 + r0 + i;
    if (n < NN) {
      st4(&A[(size_t)n * D + o0],     make_float4(acc[i][0], acc[i][1], acc[i][2], acc[i][3]));
      st4(&A[(size_t)n * D + o0 + 4], make_float4(acc[i][4], acc[i][5], acc[i][6], acc[i][7]));
    }
  }

  // ---- B ----
  zero_acc<2>(acc);
  gemm_tile<2>(X, ew1 + 128, IND, r0, o0, acc);
#pragma unroll
  for (int i = 0; i < 2; ++i) {
    int n = n0 + r0 + i;
    if (n < NN) {
      st4(&B[(size_t)n * D + o0],     make_float4(acc[i][0], acc[i][1], acc[i][2], acc[i][3]));
      st4(&B[(size_t)n * D + o0 + 4], make_float4(acc[i][4], acc[i][5], acc[i][6], acc[i][7]));
    }
  }

  // ---- M layer 1: h1 = relu(mw1.z + mb1), swapped through LDS ----
  zero_acc<2>(acc);
  gemm_tile<2>(X, mw1, D, r0, o0, acc);
  __syncthreads();  // everyone done reading z-tile
#pragma unroll
  for (int i = 0; i < 2; ++i)
#pragma unroll
    for (int j = 0; j < 8; ++j)
      X[r0 + i][o0 + j] = fmaxf(acc[i][j] + mb1[o0 + j], 0.0f);
  __syncthreads();

  // ---- M layer 2 ----
  zero_acc<2>(acc);
  gemm_tile<2>(X, mw2, D, r0, o0, acc);
#pragma unroll
  for (int i = 0; i < 2; ++i) {
    int n = n0 + r0 + i;
    if (n < NN) {
      st4(&M[(size_t)n * D + o0],
          make_float4(acc[i][0] + mb2[o0 + 0], acc[i][1] + mb2[o0 + 1],
                      acc[i][2] + mb2[o0 + 2], acc[i][3] + mb2[o0 + 3]));
      st4(&M[(size_t)n * D + o0 + 4],
          make_float4(acc[i][4] + mb2[o0 + 4], acc[i][5] + mb2[o0 + 5],
                      acc[i][6] + mb2[o0 + 6], acc[i][7] + mb2[o0 + 7]));
    }
  }
}

// ---------------------------------------------------------------------------
// K2: per-edge pass. 32 edges/block (LDS 18.3KB -> 8 blocks/CU = 100% occ).
//   hc = Wc . |z[src]-z[dst]|
//   h  = relu(hc + A[src] + B[dst] + tvec[type] + eb1)
//   w  = sigmoid(h . ew2 + eb2);  wexp[e] = exp(w)   (no atomics)
// (max-subtraction dropped: w in (0,1) so exp(w) is stable.)
// ---------------------------------------------------------------------------
__global__ __launch_bounds__(256, 8) void k_edge(
    const float* __restrict__ z, const int* __restrict__ ei,
    const int* __restrict__ etype, const float* __restrict__ type_emb,
    const float* __restrict__ ew1, const float* __restrict__ eb1,
    const float* __restrict__ ew2, const float* __restrict__ eb2,
    const float* __restrict__ A, const float* __restrict__ B,
    float* __restrict__ wexp)
{
  __shared__ float X[32][132];
  __shared__ float tv[2][128];
  __shared__ int   se[32], de[32], tye[32];

  const int t  = threadIdx.x;
  const int e0 = blockIdx.x * 32;

  // type-embedding contribution: tv[ty][o] = sum_j ew1[o][384+j]*type_emb[ty][j]
  {
    int o = t & 127, ty = t >> 7;
    float s = 0.f;
#pragma unroll
    for (int j = 0; j < 8; ++j) s += ew1[o * IND + 384 + j] * type_emb[ty * 8 + j];
    tv[ty][o] = s;
  }
  if (t < 32) {
    se[t]  = ei[e0 + t];
    de[t]  = ei[NE + e0 + t];
    tye[t] = etype[e0 + t];
  }
  __syncthreads();

  // stage |z[src]-z[dst]| (32 lanes cover one 512B row -> coalesced gather)
#pragma unroll
  for (int c = 0; c < 4; ++c) {
    int f = c * 256 + t, r = f >> 5, c4 = f & 31;
    float4 a = ld4(&z[(size_t)se[r] * D + c4 * 4]);
    float4 b = ld4(&z[(size_t)de[r] * D + c4 * 4]);
    st4(&X[r][c4 * 4], make_float4(fabsf(a.x - b.x), fabsf(a.y - b.y),
                                   fabsf(a.z - b.z), fabsf(a.w - b.w)));
  }
  __syncthreads();

  const int r0 = (t >> 4) * 2;
  const int o0 = (t & 15) * 8;
  float acc[2][8];
  zero_acc<2>(acc);
  gemm_tile<2>(X, ew1 + 256, IND, r0, o0, acc);  // Wc term

  // epilogue: finish h for my (2 edges x 8 outs), partial dot with ew2
  float4 c0 = ld4(&eb1[o0]), c1 = ld4(&eb1[o0 + 4]);
  float4 w0 = ld4(&ew2[o0]), w1 = ld4(&ew2[o0 + 4]);
  float p[2];
#pragma unroll
  for (int i = 0; i < 2; ++i) {
    int el = r0 + i;
    int s = se[el], dd = de[el], ty = tye[el];
    float4 a0 = ld4(&A[(size_t)s * D + o0]),  a1 = ld4(&A[(size_t)s * D + o0 + 4]);
    float4 b0 = ld4(&B[(size_t)dd * D + o0]), b1 = ld4(&B[(size_t)dd * D + o0 + 4]);
    float4 t0 = ld4(&tv[ty][o0]),             t1 = ld4(&tv[ty][o0 + 4]);
    float pp = 0.f, h;
    h = acc[i][0] + a0.x + b0.x + t0.x + c0.x; pp += fmaxf(h, 0.f) * w0.x;
    h = acc[i][1] + a0.y + b0.y + t0.y + c0.y; pp += fmaxf(h, 0.f) * w0.y;
    h = acc[i][2] + a0.z + b0.z + t0.z + c0.z; pp += fmaxf(h, 0.f) * w0.z;
    h = acc[i][3] + a0.w + b0.w + t0.w + c0.w; pp += fmaxf(h, 0.f) * w0.w;
    h = acc[i][4] + a1.x + b1.x + t1.x + c1.x; pp += fmaxf(h, 0.f) * w1.x;
    h = acc[i][5] + a1.y + b1.y + t1.y + c1.y; pp += fmaxf(h, 0.f) * w1.y;
    h = acc[i][6] + a1.z + b1.z + t1.z + c1.z; pp += fmaxf(h, 0.f) * w1.z;
    h = acc[i][7] + a1.w + b1.w + t1.w + c1.w; pp += fmaxf(h, 0.f) * w1.w;
    p[i] = pp;
  }

  // reduce over the 16 o-groups (lanes t&15 within contiguous 16-lane group)
#pragma unroll
  for (int m = 1; m < 16; m <<= 1) {
    p[0] += __shfl_xor(p[0], m);
    p[1] += __shfl_xor(p[1], m);
  }
  if ((t & 15) == 0) {
    float b2 = eb2[0];
#pragma unroll
    for (int i = 0; i < 2; ++i) {
      float w = 1.0f / (1.0f + expf(-(p[i] + b2)));  // sigmoid
      wexp[e0 + r0 + i] = expf(w);
    }
  }
}

// ---------------------------------------------------------------------------
// CSR build: histogram -> single-block scan -> fill
// ---------------------------------------------------------------------------
__global__ __launch_bounds__(256) void k_hist(const int* __restrict__ ei,
                                              int* __restrict__ deg)
{
  int e = blockIdx.x * 256 + threadIdx.x;
  if (e < NE) atomicAdd(&deg[ei[e]], 1);
}

__global__ __launch_bounds__(1024) void k_scan(const int* __restrict__ deg,
                                               int* __restrict__ rowptr,
                                               int* __restrict__ cursor)
{
  __shared__ int ps[1024];
  const int t = threadIdx.x;
  const int CH = 49;  // 1024*49 = 50176 >= NN
  int lo = t * CH, hi = min(lo + CH, NN);
  int s = 0;
  for (int i = lo; i < hi; ++i) s += deg[i];
  ps[t] = s;
  __syncthreads();
  for (int off = 1; off < 1024; off <<= 1) {
    int v = (t >= off) ? ps[t - off] : 0;
    __syncthreads();
    ps[t] += v;
    __syncthreads();
  }
  int run = t ? ps[t - 1] : 0;  // exclusive prefix of my chunk
  for (int i = lo; i < hi; ++i) {
    rowptr[i] = run;
    cursor[i] = run;
    run += deg[i];
  }
  if (t == 1023) rowptr[NN] = NE;
}

__global__ __launch_bounds__(256) void k_fill(const int* __restrict__ ei,
                                              int* __restrict__ cursor,
                                              int* __restrict__ eid)
{
  int e = blockIdx.x * 256 + threadIdx.x;
  if (e < NE) {
    int pos = atomicAdd(&cursor[ei[e]], 1);
    eid[pos] = e;
  }
}

// ---------------------------------------------------------------------------
// K3: fused per-node aggregation + residual + LayerNorm. One wave per node.
//   sum  = sum_e wexp[e]            (edges of node, no atomics)
//   alpha= wexp/(sum+1e-12); alpha_out[e]=alpha
//   acc  = sum_e alpha * M[dst[e]]
//   out[n] = LN(z[n] + acc) * gamma + beta
// lane l owns 2 of the 128 features (float2).
// ---------------------------------------------------------------------------
__global__ __launch_bounds__(256) void k_agg(
    const float* __restrict__ z, const int* __restrict__ ei,
    const float* __restrict__ wexp, const float* __restrict__ M,
    const int* __restrict__ rowptr, const int* __restrict__ eid,
    const float* __restrict__ gamma, const float* __restrict__ beta,
    float* __restrict__ out, float* __restrict__ alpha_out)
{
  const int t = threadIdx.x;
  const int n = blockIdx.x * 4 + (t >> 6);
  const int l = t & 63;
  const int start = rowptr[n], end = rowptr[n + 1];
  const float2* M2 = reinterpret_cast<const float2*>(M);

  // pass 1: total wexp over the node's edges
  float tot = 0.f;
  for (int base = start; base < end; base += 64) {
    float we = 0.f;
    if (base + l < end) we = wexp[eid[base + l]];
    tot += we;
  }
#pragma unroll
  for (int off = 32; off; off >>= 1) tot += __shfl_xor(tot, off);
  const float inv = 1.0f / (tot + 1e-12f);

  // pass 2: alpha + weighted aggregation of M[dst]
  float2 acc = make_float2(0.f, 0.f);
  for (int base = start; base < end; base += 64) {
    int cnt = min(64, end - base);
    int e = 0, dd = 0;
    float al = 0.f;
    if (l < cnt) {
      e  = eid[base + l];
      al = wexp[e] * inv;
      dd = ei[NE + e];
      alpha_out[e] = al;
    }
    for (int i = 0; i < cnt; ++i) {
      float a = __shfl(al, i);
      int   d = __shfl(dd, i);
      float2 m = M2[(size_t)d * 64 + l];
      acc.x = fmaf(a, m.x, acc.x);
      acc.y = fmaf(a, m.y, acc.y);
    }
  }

  // residual + LayerNorm
  float2 xz = *reinterpret_cast<const float2*>(&z[(size_t)n * D + l * 2]);
  float x0 = xz.x + acc.x, x1 = xz.y + acc.y;
  float s = x0 + x1;
#pragma unroll
  for (int off = 32; off; off >>= 1) s += __shfl_xor(s, off);
  const float mu = s * (1.0f / 128.0f);
  float d0 = x0 - mu, d1 = x1 - mu;
  float q = d0 * d0 + d1 * d1;
#pragma unroll
  for (int off = 32; off; off >>= 1) q += __shfl_xor(q, off);
  const float rstd = rsqrtf(q * (1.0f / 128.0f) + 1e-5f);
  float2 g = *reinterpret_cast<const float2*>(&gamma[l * 2]);
  float2 b = *reinterpret_cast<const float2*>(&beta[l * 2]);
  float2 o = make_float2(d0 * rstd * g.x + b.x, d1 * rstd * g.y + b.y);
  *reinterpret_cast<float2*>(&out[(size_t)n * D + l * 2]) = o;
}

// ---------------------------------------------------------------------------
extern "C" void kernel_launch(void* const* d_in, const int* in_sizes, int n_in,
                              void* d_out, int out_size, void* d_ws, size_t ws_size,
                              hipStream_t stream)
{
  const float* z        = (const float*)d_in[0];
  const int*   ei       = (const int*)d_in[1];   // [2,E]: src row, then dst row
  const int*   etype    = (const int*)d_in[2];
  const float* type_emb = (const float*)d_in[3];
  const float* ew1      = (const float*)d_in[4];
  const float* eb1      = (const float*)d_in[5];
  const float* ew2      = (const float*)d_in[6];
  const float* eb2      = (const float*)d_in[7];
  const float* mw1      = (const float*)d_in[8];
  const float* mb1      = (const float*)d_in[9];
  const float* mw2      = (const float*)d_in[10];
  const float* mb2      = (const float*)d_in[11];
  const float* gamma    = (const float*)d_in[12];
  const float* beta     = (const float*)d_in[13];

  // workspace layout: A | B | M (f32) | wexp (f32) | deg | rowptr | cursor | eid (int)
  float* ws     = (float*)d_ws;
  float* A      = ws;
  float* B      = ws + 6400000;
  float* M      = ws + 12800000;
  float* wexp   = ws + 19200000;
  int*   deg    = (int*)(ws + 19800000);
  int*   rowptr = deg + 50000;
  int*   cursor = rowptr + 50004;   // 50001 used, padded
  int*   eid    = cursor + 50000;

  float* out       = (float*)d_out;
  float* alpha_out = out + (size_t)NN * D;

  hipMemsetAsync(deg, 0, 50000 * sizeof(int), stream);

  k_node<<<(NN + 31) / 32, 256, 0, stream>>>(z, ew1, mw1, mb1, mw2, mb2, A, B, M);
  k_edge<<<NE / 32, 256, 0, stream>>>(z, ei, etype, type_emb, ew1, eb1, ew2, eb2,
                                      A, B, wexp);
  k_hist<<<(NE + 255) / 256, 256, 0, stream>>>(ei, deg);
  k_scan<<<1, 1024, 0, stream>>>(deg, rowptr, cursor);
  k_fill<<<(NE + 255) / 256, 256, 0, stream>>>(ei, cursor, eid);
  k_agg<<<NN / 4, 256, 0, stream>>>(z, ei, wexp, M, rowptr, eid,
                                    gamma, beta, out, alpha_out);
}

// Round 3
// 1804.992 us; speedup vs baseline: 1.9077x; 1.9077x over previous
//
#include <hip/hip_runtime.h>
#include <math.h>

// Problem constants (fixed by the reference)
constexpr int NN  = 50000;   // nodes
constexpr int NE  = 600000;  // edges
constexpr int D   = 128;     // DIM == HID
constexpr int IND = 392;     // 3*DIM + TEMB

__device__ __forceinline__ float4 ld4(const float* p) { return *reinterpret_cast<const float4*>(p); }
__device__ __forceinline__ void   st4(float* p, float4 v) { *reinterpret_cast<float4*>(p) = v; }

// ---------------------------------------------------------------------------
// GEMM tile core: C[64 rows][128 outs] += X[64][128k] * W[128 outs][128k]^T
// per-thread register tile: 4 rows x 8 outputs. X in LDS (rows padded to 132
// floats -> worst LDS read aliasing is 2-way = free). W rows streamed from
// global; 64KB slice shared by the whole block -> L2-resident.
// ---------------------------------------------------------------------------
__device__ __forceinline__ void gemm_tile(const float (*X)[132],
                                          const float* __restrict__ W, int ldw,
                                          int r0, int o0, float acc[4][8])
{
#pragma unroll 2
  for (int k = 0; k < 128; k += 4) {
    float4 x[4];
#pragma unroll
    for (int i = 0; i < 4; ++i) x[i] = ld4(&X[r0 + i][k]);
#pragma unroll
    for (int j = 0; j < 8; ++j) {
      float4 w = ld4(&W[(o0 + j) * ldw + k]);
#pragma unroll
      for (int i = 0; i < 4; ++i) {
        acc[i][j] = fmaf(x[i].x, w.x, acc[i][j]);
        acc[i][j] = fmaf(x[i].y, w.y, acc[i][j]);
        acc[i][j] = fmaf(x[i].z, w.z, acc[i][j]);
        acc[i][j] = fmaf(x[i].w, w.w, acc[i][j]);
      }
    }
  }
}

__device__ __forceinline__ void zero_acc(float acc[4][8]) {
#pragma unroll
  for (int i = 0; i < 4; ++i)
#pragma unroll
    for (int j = 0; j < 8; ++j) acc[i][j] = 0.0f;
}

// ---------------------------------------------------------------------------
// K1: per-node precompute (round-0 geometry: 64 nodes/block, no spills).
//   A[n]  = ew1[:,   0:128] . z[n]
//   B[n]  = ew1[:, 128:256] . z[n]
//   M[n]  = mw2 . relu(mw1 . z[n] + mb1) + mb2
// ---------------------------------------------------------------------------
__global__ __launch_bounds__(256, 4) void k_node(
    const float* __restrict__ z, const float* __restrict__ ew1,
    const float* __restrict__ mw1, const float* __restrict__ mb1,
    const float* __restrict__ mw2, const float* __restrict__ mb2,
    float* __restrict__ A, float* __restrict__ B, float* __restrict__ M)
{
  __shared__ float X[64][132];
  const int t  = threadIdx.x;
  const int n0 = blockIdx.x * 64;

#pragma unroll
  for (int c = 0; c < 8; ++c) {
    int f = c * 256 + t, r = f >> 5, c4 = f & 31;
    float4 v = make_float4(0.f, 0.f, 0.f, 0.f);
    if (n0 + r < NN) v = ld4(&z[(size_t)(n0 + r) * D + c4 * 4]);
    st4(&X[r][c4 * 4], v);
  }
  __syncthreads();

  const int r0 = (t >> 4) * 4;
  const int o0 = (t & 15) * 8;
  float acc[4][8];

  // ---- A ----
  zero_acc(acc);
  gemm_tile(X, ew1, IND, r0, o0, acc);
#pragma unroll
  for (int i = 0; i < 4; ++i) {
    int n = n0 + r0 + i;
    if (n < NN) {
      st4(&A[(size_t)n * D + o0],     make_float4(acc[i][0], acc[i][1], acc[i][2], acc[i][3]));
      st4(&A[(size_t)n * D + o0 + 4], make_float4(acc[i][4], acc[i][5], acc[i][6], acc[i][7]));
    }
  }

  // ---- B ----
  zero_acc(acc);
  gemm_tile(X, ew1 + 128, IND, r0, o0, acc);
#pragma unroll
  for (int i = 0; i < 4; ++i) {
    int n = n0 + r0 + i;
    if (n < NN) {
      st4(&B[(size_t)n * D + o0],     make_float4(acc[i][0], acc[i][1], acc[i][2], acc[i][3]));
      st4(&B[(size_t)n * D + o0 + 4], make_float4(acc[i][4], acc[i][5], acc[i][6], acc[i][7]));
    }
  }

  // ---- M layer 1: h1 = relu(mw1.z + mb1), swapped through LDS ----
  zero_acc(acc);
  gemm_tile(X, mw1, D, r0, o0, acc);
  __syncthreads();
#pragma unroll
  for (int i = 0; i < 4; ++i)
#pragma unroll
    for (int j = 0; j < 8; ++j)
      X[r0 + i][o0 + j] = fmaxf(acc[i][j] + mb1[o0 + j], 0.0f);
  __syncthreads();

  // ---- M layer 2 ----
  zero_acc(acc);
  gemm_tile(X, mw2, D, r0, o0, acc);
#pragma unroll
  for (int i = 0; i < 4; ++i) {
    int n = n0 + r0 + i;
    if (n < NN) {
      st4(&M[(size_t)n * D + o0],
          make_float4(acc[i][0] + mb2[o0 + 0], acc[i][1] + mb2[o0 + 1],
                      acc[i][2] + mb2[o0 + 2], acc[i][3] + mb2[o0 + 3]));
      st4(&M[(size_t)n * D + o0 + 4],
          make_float4(acc[i][4] + mb2[o0 + 4], acc[i][5] + mb2[o0 + 5],
                      acc[i][6] + mb2[o0 + 6], acc[i][7] + mb2[o0 + 7]));
    }
  }
}

// ---------------------------------------------------------------------------
// CSR build: histogram -> single-block scan -> fill (stores eid + dst)
// ---------------------------------------------------------------------------
__global__ __launch_bounds__(256) void k_hist(const int* __restrict__ ei,
                                              int* __restrict__ deg)
{
  int e = blockIdx.x * 256 + threadIdx.x;
  if (e < NE) atomicAdd(&deg[ei[e]], 1);
}

__global__ __launch_bounds__(1024) void k_scan(const int* __restrict__ deg,
                                               int* __restrict__ rowptr,
                                               int* __restrict__ cursor)
{
  __shared__ int ps[1024];
  const int t = threadIdx.x;
  const int CH = 49;  // 1024*49 = 50176 >= NN
  int lo = t * CH, hi = min(lo + CH, NN);
  if (lo > NN) { lo = NN; hi = NN; }
  int s = 0;
  for (int i = lo; i < hi; ++i) s += deg[i];
  ps[t] = s;
  __syncthreads();
  for (int off = 1; off < 1024; off <<= 1) {
    int v = (t >= off) ? ps[t - off] : 0;
    __syncthreads();
    ps[t] += v;
    __syncthreads();
  }
  int run = t ? ps[t - 1] : 0;
  for (int i = lo; i < hi; ++i) {
    rowptr[i] = run;
    cursor[i] = run;
    run += deg[i];
  }
  if (t == 1023) rowptr[NN] = NE;
}

__global__ __launch_bounds__(256) void k_fill(const int* __restrict__ ei,
                                              int* __restrict__ cursor,
                                              int* __restrict__ eid,
                                              int* __restrict__ de_perm)
{
  int e = blockIdx.x * 256 + threadIdx.x;
  if (e < NE) {
    int pos = atomicAdd(&cursor[ei[e]], 1);
    eid[pos] = e;
    de_perm[pos] = ei[NE + e];
  }
}

// ---------------------------------------------------------------------------
// K2: per-edge pass in CSR (src-sorted) order. 64 positions/block.
//   hc = Wc . |z[src]-z[dst]|
//   h  = relu(hc + A[src] + B[dst] + tvec[type] + eb1)
//   wexp_perm[pos] = exp(sigmoid(h . ew2 + eb2))
// src side is ~sequential (L1-hot); B[dst] prefetched to registers before
// the GEMM so its latency hides under the FMA stream.
// ---------------------------------------------------------------------------
__global__ __launch_bounds__(256, 4) void k_edge(
    const float* __restrict__ z, const int* __restrict__ ei,
    const int* __restrict__ etype, const float* __restrict__ type_emb,
    const float* __restrict__ ew1, const float* __restrict__ eb1,
    const float* __restrict__ ew2, const float* __restrict__ eb2,
    const float* __restrict__ A, const float* __restrict__ B,
    const int* __restrict__ eid, const int* __restrict__ de_perm,
    float* __restrict__ wexp_perm)
{
  __shared__ float X[64][132];
  __shared__ float tv[2][128];
  __shared__ int   se[64], de[64], tye[64];

  const int t  = threadIdx.x;
  const int e0 = blockIdx.x * 64;

  // tv[ty][o] = sum_j ew1[o][384+j]*type_emb[ty][j]
  {
    int o = t & 127, ty = t >> 7;
    float s = 0.f;
#pragma unroll
    for (int j = 0; j < 8; ++j) s += ew1[o * IND + 384 + j] * type_emb[ty * 8 + j];
    tv[ty][o] = s;
  }
  if (t < 64) {
    int e = eid[e0 + t];
    se[t]  = ei[e];
    de[t]  = de_perm[e0 + t];
    tye[t] = etype[e];
  }
  __syncthreads();

  const int r0 = (t >> 4) * 4;
  const int o0 = (t & 15) * 8;

  // prefetch B[dst] (the random side) into registers
  float4 bPre[4][2];
#pragma unroll
  for (int i = 0; i < 4; ++i) {
    int dd = de[r0 + i];
    bPre[i][0] = ld4(&B[(size_t)dd * D + o0]);
    bPre[i][1] = ld4(&B[(size_t)dd * D + o0 + 4]);
  }

  // stage |z[src]-z[dst]| (src rows L1-hot thanks to CSR order)
#pragma unroll
  for (int c = 0; c < 8; ++c) {
    int f = c * 256 + t, r = f >> 5, c4 = f & 31;
    float4 a = ld4(&z[(size_t)se[r] * D + c4 * 4]);
    float4 b = ld4(&z[(size_t)de[r] * D + c4 * 4]);
    st4(&X[r][c4 * 4], make_float4(fabsf(a.x - b.x), fabsf(a.y - b.y),
                                   fabsf(a.z - b.z), fabsf(a.w - b.w)));
  }
  __syncthreads();

  float acc[4][8];
  zero_acc(acc);
  gemm_tile(X, ew1 + 256, IND, r0, o0, acc);  // Wc term

  float4 c0 = ld4(&eb1[o0]), c1 = ld4(&eb1[o0 + 4]);
  float4 w0 = ld4(&ew2[o0]), w1 = ld4(&ew2[o0 + 4]);
  float p[4];
#pragma unroll
  for (int i = 0; i < 4; ++i) {
    int el = r0 + i;
    int s = se[el], ty = tye[el];
    float4 a0 = ld4(&A[(size_t)s * D + o0]), a1 = ld4(&A[(size_t)s * D + o0 + 4]);
    float4 t0 = ld4(&tv[ty][o0]),            t1 = ld4(&tv[ty][o0 + 4]);
    float pp = 0.f, h;
    h = acc[i][0] + a0.x + bPre[i][0].x + t0.x + c0.x; pp += fmaxf(h, 0.f) * w0.x;
    h = acc[i][1] + a0.y + bPre[i][0].y + t0.y + c0.y; pp += fmaxf(h, 0.f) * w0.y;
    h = acc[i][2] + a0.z + bPre[i][0].z + t0.z + c0.z; pp += fmaxf(h, 0.f) * w0.z;
    h = acc[i][3] + a0.w + bPre[i][0].w + t0.w + c0.w; pp += fmaxf(h, 0.f) * w0.w;
    h = acc[i][4] + a1.x + bPre[i][1].x + t1.x + c1.x; pp += fmaxf(h, 0.f) * w1.x;
    h = acc[i][5] + a1.y + bPre[i][1].y + t1.y + c1.y; pp += fmaxf(h, 0.f) * w1.y;
    h = acc[i][6] + a1.z + bPre[i][1].z + t1.z + c1.z; pp += fmaxf(h, 0.f) * w1.z;
    h = acc[i][7] + a1.w + bPre[i][1].w + t1.w + c1.w; pp += fmaxf(h, 0.f) * w1.w;
    p[i] = pp;
  }

  // reduce over the 16 o-groups (lanes within each 16-lane group)
#pragma unroll
  for (int m = 1; m < 16; m <<= 1) {
#pragma unroll
    for (int i = 0; i < 4; ++i) p[i] += __shfl_xor(p[i], m);
  }
  if ((t & 15) == 0) {
    float b2 = eb2[0];
#pragma unroll
    for (int i = 0; i < 4; ++i) {
      float w = 1.0f / (1.0f + expf(-(p[i] + b2)));  // sigmoid
      wexp_perm[e0 + r0 + i] = expf(w);              // w in (0,1): no max needed
    }
  }
}

// ---------------------------------------------------------------------------
// K3: fused per-node aggregation + residual + LayerNorm. One wave per node.
// wexp_perm is contiguous per node (CSR); de_perm gives dst directly.
// ---------------------------------------------------------------------------
__global__ __launch_bounds__(256) void k_agg(
    const float* __restrict__ z, const float* __restrict__ wexp_perm,
    const float* __restrict__ M, const int* __restrict__ rowptr,
    const int* __restrict__ eid, const int* __restrict__ de_perm,
    const float* __restrict__ gamma, const float* __restrict__ beta,
    float* __restrict__ out, float* __restrict__ alpha_out)
{
  const int t = threadIdx.x;
  const int n = blockIdx.x * 4 + (t >> 6);
  const int l = t & 63;
  const int start = rowptr[n], end = rowptr[n + 1];
  const float2* M2 = reinterpret_cast<const float2*>(M);

  // pass 1: total wexp over the node's edges (contiguous reads)
  float tot = 0.f;
  for (int base = start; base < end; base += 64) {
    if (base + l < end) tot += wexp_perm[base + l];
  }
#pragma unroll
  for (int off = 32; off; off >>= 1) tot += __shfl_xor(tot, off);
  const float inv = 1.0f / (tot + 1e-12f);

  // pass 2: alpha + weighted aggregation of M[dst]
  float2 acc = make_float2(0.f, 0.f);
  for (int base = start; base < end; base += 64) {
    int cnt = min(64, end - base);
    int dd = 0;
    float al = 0.f;
    if (l < cnt) {
      int pos = base + l;
      al = wexp_perm[pos] * inv;
      dd = de_perm[pos];
      alpha_out[eid[pos]] = al;
    }
    for (int i = 0; i < cnt; ++i) {
      float a = __shfl(al, i);
      int   d = __shfl(dd, i);
      float2 m = M2[(size_t)d * 64 + l];
      acc.x = fmaf(a, m.x, acc.x);
      acc.y = fmaf(a, m.y, acc.y);
    }
  }

  // residual + LayerNorm
  float2 xz = *reinterpret_cast<const float2*>(&z[(size_t)n * D + l * 2]);
  float x0 = xz.x + acc.x, x1 = xz.y + acc.y;
  float s = x0 + x1;
#pragma unroll
  for (int off = 32; off; off >>= 1) s += __shfl_xor(s, off);
  const float mu = s * (1.0f / 128.0f);
  float d0 = x0 - mu, d1 = x1 - mu;
  float q = d0 * d0 + d1 * d1;
#pragma unroll
  for (int off = 32; off; off >>= 1) q += __shfl_xor(q, off);
  const float rstd = rsqrtf(q * (1.0f / 128.0f) + 1e-5f);
  float2 g = *reinterpret_cast<const float2*>(&gamma[l * 2]);
  float2 b = *reinterpret_cast<const float2*>(&beta[l * 2]);
  float2 o = make_float2(d0 * rstd * g.x + b.x, d1 * rstd * g.y + b.y);
  *reinterpret_cast<float2*>(&out[(size_t)n * D + l * 2]) = o;
}

// ---------------------------------------------------------------------------
extern "C" void kernel_launch(void* const* d_in, const int* in_sizes, int n_in,
                              void* d_out, int out_size, void* d_ws, size_t ws_size,
                              hipStream_t stream)
{
  const float* z        = (const float*)d_in[0];
  const int*   ei       = (const int*)d_in[1];   // [2,E]: src row, then dst row
  const int*   etype    = (const int*)d_in[2];
  const float* type_emb = (const float*)d_in[3];
  const float* ew1      = (const float*)d_in[4];
  const float* eb1      = (const float*)d_in[5];
  const float* ew2      = (const float*)d_in[6];
  const float* eb2      = (const float*)d_in[7];
  const float* mw1      = (const float*)d_in[8];
  const float* mb1      = (const float*)d_in[9];
  const float* mw2      = (const float*)d_in[10];
  const float* mb2      = (const float*)d_in[11];
  const float* gamma    = (const float*)d_in[12];
  const float* beta     = (const float*)d_in[13];

  // workspace: A | B | M | wexp_perm (f32) || deg | rowptr | cursor | eid | de_perm (int)
  float* ws        = (float*)d_ws;
  float* A         = ws;
  float* B         = ws + 6400000;
  float* M         = ws + 12800000;
  float* wexp_perm = ws + 19200000;
  int*   deg       = (int*)(ws + 19800000);
  int*   rowptr    = deg + 50000;
  int*   cursor    = rowptr + 50004;
  int*   eid       = cursor + 50000;
  int*   de_perm   = eid + 600000;

  float* out       = (float*)d_out;
  float* alpha_out = out + (size_t)NN * D;

  hipMemsetAsync(deg, 0, 50000 * sizeof(int), stream);

  k_hist<<<(NE + 255) / 256, 256, 0, stream>>>(ei, deg);
  k_scan<<<1, 1024, 0, stream>>>(deg, rowptr, cursor);
  k_fill<<<(NE + 255) / 256, 256, 0, stream>>>(ei, cursor, eid, de_perm);
  k_node<<<(NN + 63) / 64, 256, 0, stream>>>(z, ew1, mw1, mb1, mw2, mb2, A, B, M);
  k_edge<<<NE / 64, 256, 0, stream>>>(z, ei, etype, type_emb, ew1, eb1, ew2, eb2,
                                      A, B, eid, de_perm, wexp_perm);
  k_agg<<<NN / 4, 256, 0, stream>>>(z, wexp_perm, M, rowptr, eid, de_perm,
                                    gamma, beta, out, alpha_out);
}